// Round 1
// 416.779 us; speedup vs baseline: 1.0230x; 1.0230x over previous
//
#include <hip/hip_runtime.h>

// Haar DWT along S for x[B=32, S=4096, C=512] fp32.
// out[b, i, c]       = (x[b,2i,c] + x[b,2i+1,c]) / sqrt2   for i in [0, S/2)
// out[b, S/2+i, c]   = (x[b,2i,c] - x[b,2i+1,c]) / sqrt2
//
// Memory-bound streaming: 256 MiB in + 256 MiB out, zero reuse.
// This version: compile-time geometry (shift/mask indexing), 64 B per thread
// (4-deep float4 load ILP), uniform grid-stride (no tail), nontemporal
// loads/stores (no L2 allocation for single-use streams).

typedef float f4 __attribute__((ext_vector_type(4)));

constexpr int kB    = 32;
constexpr int kS    = 4096;
constexpr int kC    = 512;
constexpr int kHalf = kS / 2;                  // 2048 pairs per batch
constexpr int kC4   = kC / 4;                  // 128 float4 per row
constexpr int kChunk = kC4 / 2;                // 64: thread covers cols c and c+64
constexpr int kTotal = kB * kHalf * kChunk;    // 4,194,304 work items

__global__ __launch_bounds__(256) void haar_dwt_kernel(
    const f4* __restrict__ x, f4* __restrict__ out) {
  const float inv_sqrt2 = 0.70710678118654752440f;

  const int stride = gridDim.x * blockDim.x;
  for (int idx = blockIdx.x * blockDim.x + threadIdx.x; idx < kTotal;
       idx += stride) {
    const int c  = idx & (kChunk - 1);         // column chunk [0, 64)
    const int bi = idx >> 6;                   // b*kHalf + i, in [0, 65536)

    // Input rows 2i and 2i+1 of batch b: row index b*S + 2i == 2*bi.
    const f4* r0 = x + (size_t)(2 * bi) * kC4;
    f4 a0 = __builtin_nontemporal_load(&r0[c]);
    f4 a1 = __builtin_nontemporal_load(&r0[c + kChunk]);
    f4 b0 = __builtin_nontemporal_load(&r0[kC4 + c]);
    f4 b1 = __builtin_nontemporal_load(&r0[kC4 + c + kChunk]);

    f4 s0 = (a0 + b0) * inv_sqrt2;
    f4 s1 = (a1 + b1) * inv_sqrt2;
    f4 d0 = (a0 - b0) * inv_sqrt2;
    f4 d1 = (a1 - b1) * inv_sqrt2;

    // Output rows: cA at b*S + i, cD at b*S + kHalf + i.
    // b*S + i = bi + b*kHalf = bi + (bi & ~(kHalf-1)).
    const int rowA = bi + (bi & ~(kHalf - 1));
    f4* oa = out + (size_t)rowA * kC4;
    f4* od = oa + (size_t)kHalf * kC4;
    __builtin_nontemporal_store(s0, &oa[c]);
    __builtin_nontemporal_store(s1, &oa[c + kChunk]);
    __builtin_nontemporal_store(d0, &od[c]);
    __builtin_nontemporal_store(d1, &od[c + kChunk]);
  }
}

extern "C" void kernel_launch(void* const* d_in, const int* in_sizes, int n_in,
                              void* d_out, int out_size, void* d_ws,
                              size_t ws_size, hipStream_t stream) {
  const f4* x = (const f4*)d_in[0];
  f4* out = (f4*)d_out;

  // 4096 blocks x 256 threads = 1,048,576 threads; kTotal/threads = 4 exact
  // iterations per thread (uniform, no tail divergence).
  const int block = 256;
  const int grid = 4096;
  haar_dwt_kernel<<<grid, block, 0, stream>>>(x, out);
}